// Round 1
// baseline (26183.905 us; speedup 1.0000x reference)
//
#include <hip/hip_runtime.h>

// Sizes
#define BB 32
#define TT 1024
#define INF 64
#define H1 512
#define G4 2048          // 4*H1
#define H2 256
#define NBLOCKS 256
#define NL 128           // blocks per layer
#define HSEQ 16777216    // 32*1024*512

typedef __attribute__((ext_vector_type(8))) __bf16 bf16x8;
typedef __attribute__((ext_vector_type(4))) float f32x4;

// x (B,T,64) f32 -> xbf [t][m][64] bf16
__global__ __launch_bounds__(256) void prep_x(const float* __restrict__ x,
                                              __bf16* __restrict__ xbf) {
    int idx = blockIdx.x * 256 + threadIdx.x;      // 0..524287, float4 units
    int k4 = idx & 15;
    int t  = (idx >> 4) & 1023;
    int m  = idx >> 14;
    float4 v = ((const float4*)x)[idx];
    __bf16* d = xbf + (size_t)t * 2048 + m * 64 + k4 * 4;
    d[0] = (__bf16)v.x; d[1] = (__bf16)v.y; d[2] = (__bf16)v.z; d[3] = (__bf16)v.w;
}

__device__ inline float sigf(float v) { return 1.f / (1.f + expf(-v)); }

// Persistent 2-layer LSTM. Blocks [0,128): layer0 step s. Blocks [128,256): layer1 step s-1.
__global__ __launch_bounds__(256, 1) void lstm_kernel(
    const __bf16* __restrict__ xbf,
    const float* __restrict__ Wih0, const float* __restrict__ Whh0,
    const float* __restrict__ bih0, const float* __restrict__ bhh0,
    const float* __restrict__ Wih1, const float* __restrict__ Whh1,
    const float* __restrict__ bih1, const float* __restrict__ bhh1,
    __bf16* __restrict__ h0buf, __bf16* __restrict__ h1buf,
    unsigned* counter, float* __restrict__ dout)
{
    __shared__ alignas(16) __bf16 wlds[32 * 512];   // packed B-fragments, up to 32 ktiles
    __shared__ float gates[2][32][16];              // [khalf][m][n]
    __shared__ float biasl[16];

    const int tid = threadIdx.x;
    const int blk = blockIdx.x;
    const bool isL1 = blk >= NL;
    const int sub = isL1 ? blk - NL : blk;
    const int hd0 = sub * 4;                        // 4 hidden dims per block
    const int KT  = isL1 ? 32 : 18;                 // k-tiles of 32 (K=1024 / K=576)
    const int KIN = isL1 ? 512 : 64;

    const float* Wih = isL1 ? Wih1 : Wih0;
    const float* Whh = isL1 ? Whh1 : Whh0;

    // ---- stage weights once: rows n=0..15 -> gate=(n>>2), hd=hd0+(n&3), packed B-frag order
    for (int e = tid; e < KT * 512; e += 256) {
        int tk = e >> 9;
        int l  = (e >> 3) & 63;
        int j  = e & 7;
        int k  = tk * 32 + ((l >> 4) << 3) + j;
        int n  = l & 15;
        int row = ((n >> 2) * 512) + hd0 + (n & 3);
        float w = (k < KIN) ? Wih[(size_t)row * KIN + k] : Whh[(size_t)row * 512 + (k - KIN)];
        wlds[e] = (__bf16)w;
    }
    if (tid < 16) {
        int row = ((tid >> 2) * 512) + hd0 + (tid & 3);
        biasl[tid] = isL1 ? (bih1[row] + bhh1[row]) : (bih0[row] + bhh0[row]);
    }
    __syncthreads();

    const int lane  = tid & 63;
    const int wv    = tid >> 6;
    const int mtile = wv & 1;
    const int khalf = wv >> 1;
    const int kth   = KT >> 1;                // 9 or 16
    const int tk0   = khalf * kth;
    const int m     = mtile * 16 + (lane & 15);
    const int koff  = (lane >> 4) << 3;       // 0,8,16,24

    const int um = tid >> 2, uq = tid & 3;    // update-phase identity (tid<128)
    const int hd = hd0 + uq;
    float creg = 0.f;

    float* hs_out = dout + 32768 + (size_t)(isL1 ? 1 : 0) * HSEQ;
    float* cs_out = dout + 32768 + (size_t)(isL1 ? 3 : 2) * HSEQ;

    unsigned bar = 0;
    for (int s = 0; s < 1025; ++s) {
        const bool active = isL1 ? (s >= 1) : (s < 1024);
        const int t = isL1 ? (s - 1) : s;

        if (active) {
            const __bf16* h_self_prev = isL1 ? (h1buf + ((s) & 1) * (32 * 512))
                                             : (h0buf + ((s + 1) & 1) * (32 * 512));
            const __bf16* h_in = isL1 ? (h0buf + ((s - 1) & 1) * (32 * 512)) : nullptr;

            f32x4 acc = {0.f, 0.f, 0.f, 0.f};
            for (int tk = tk0; tk < tk0 + kth; ++tk) {
                int kk = tk * 32 + koff;
                const __bf16* src;
                if (!isL1) {
                    src = (kk < 64) ? (xbf + (size_t)t * 2048 + m * 64 + kk)
                                    : (h_self_prev + m * 512 + (kk - 64));
                } else {
                    src = (kk < 512) ? (h_in + m * 512 + kk)
                                     : (h_self_prev + m * 512 + (kk - 512));
                }
                bf16x8 a = *(const bf16x8*)src;
                bf16x8 b = *(const bf16x8*)(wlds + (size_t)tk * 512 + lane * 8);
                acc = __builtin_amdgcn_mfma_f32_16x16x32_bf16(a, b, acc, 0, 0, 0);
            }
#pragma unroll
            for (int r = 0; r < 4; ++r) {
                int mloc = mtile * 16 + ((lane >> 4) << 2) + r;
                gates[khalf][mloc][lane & 15] = acc[r];
            }
        }
        __syncthreads();

        if (active && tid < 128) {
            float gi = gates[0][um][uq]      + gates[1][um][uq]      + biasl[uq];
            float gf = gates[0][um][4 + uq]  + gates[1][um][4 + uq]  + biasl[4 + uq];
            float gg = gates[0][um][8 + uq]  + gates[1][um][8 + uq]  + biasl[8 + uq];
            float go = gates[0][um][12 + uq] + gates[1][um][12 + uq] + biasl[12 + uq];
            float si = sigf(gi), sf = sigf(gf), so = sigf(go);
            creg = sf * creg + si * tanhf(gg);
            float h = so * tanhf(creg);
            __bf16* hb = isL1 ? (h1buf + ((s + 1) & 1) * (32 * 512))
                              : (h0buf + ((s) & 1) * (32 * 512));
            hb[um * 512 + hd] = (__bf16)h;
            hs_out[((size_t)um * 1024 + t) * 512 + hd] = h;
            cs_out[((size_t)um * 1024 + t) * 512 + hd] = creg;
        }

        if (s < 1024) {   // grid barrier
            __syncthreads();
            if (tid == 0) {
                __threadfence();
                atomicAdd(counter, 1u);
                bar += NBLOCKS;
                while (__hip_atomic_load(counter, __ATOMIC_RELAXED, __HIP_MEMORY_SCOPE_AGENT) < bar) {
                    __builtin_amdgcn_s_sleep(2);
                }
                __threadfence();
            }
            __syncthreads();
        }
    }
}

// out[tok] = W2 @ relu(W1 @ h1[tok] + b1) + b2 ; 16 tokens per block
__global__ __launch_bounds__(256) void head_kernel(
    const float* __restrict__ h1s, const float* __restrict__ W1,
    const float* __restrict__ b1,  const float* __restrict__ W2,
    const float* __restrict__ b2,  float* __restrict__ out)
{
    __shared__ alignas(16) float hl[16][512];
    __shared__ float red[16][257];
    const int tid = threadIdx.x;
    const size_t tok0 = (size_t)blockIdx.x * 16;

    const float4* src = (const float4*)(h1s + tok0 * 512);
    float4* dst = (float4*)(&hl[0][0]);
    for (int i = tid; i < 2048; i += 256) dst[i] = src[i];
    __syncthreads();

    float acc[16];
#pragma unroll
    for (int i = 0; i < 16; ++i) acc[i] = 0.f;
    const float4* wrow = (const float4*)(W1 + (size_t)tid * 512);
    for (int k4 = 0; k4 < 128; ++k4) {
        float4 w = wrow[k4];
#pragma unroll
        for (int i = 0; i < 16; ++i) {
            float4 h = ((const float4*)&hl[i][0])[k4];
            acc[i] += w.x * h.x + w.y * h.y + w.z * h.z + w.w * h.w;
        }
    }
    float w2 = W2[tid];
    float bb1 = b1[tid];
#pragma unroll
    for (int i = 0; i < 16; ++i) {
        float hid = acc[i] + bb1;
        red[i][tid] = w2 * (hid > 0.f ? hid : 0.f);
    }
    __syncthreads();
    if (tid < 16) {
        float ssum = b2[0];
        for (int j = 0; j < 256; ++j) ssum += red[tid][j];
        out[tok0 + tid] = ssum;
    }
}

extern "C" void kernel_launch(void* const* d_in, const int* in_sizes, int n_in,
                              void* d_out, int out_size, void* d_ws, size_t ws_size,
                              hipStream_t stream) {
    const float* x    = (const float*)d_in[0];
    const float* Wih0 = (const float*)d_in[1];
    const float* Whh0 = (const float*)d_in[2];
    const float* bih0 = (const float*)d_in[3];
    const float* bhh0 = (const float*)d_in[4];
    const float* Wih1 = (const float*)d_in[5];
    const float* Whh1 = (const float*)d_in[6];
    const float* bih1 = (const float*)d_in[7];
    const float* bhh1 = (const float*)d_in[8];
    const float* W1   = (const float*)d_in[9];
    const float* b1   = (const float*)d_in[10];
    const float* W2   = (const float*)d_in[11];
    const float* b2   = (const float*)d_in[12];
    float* out = (float*)d_out;

    char* ws = (char*)d_ws;
    unsigned* counter = (unsigned*)ws;
    __bf16* h0buf = (__bf16*)(ws + 256);
    __bf16* h1buf = (__bf16*)(ws + 256 + 65536);
    __bf16* xbf   = (__bf16*)(ws + 256 + 131072);

    // zero barrier counter + h double-buffers
    hipMemsetAsync(ws, 0, 256 + 131072, stream);

    prep_x<<<2048, 256, 0, stream>>>(x, xbf);

    const __bf16* xbf_c = xbf;
    void* args[] = {
        (void*)&xbf_c,
        (void*)&Wih0, (void*)&Whh0, (void*)&bih0, (void*)&bhh0,
        (void*)&Wih1, (void*)&Whh1, (void*)&bih1, (void*)&bhh1,
        (void*)&h0buf, (void*)&h1buf, (void*)&counter, (void*)&out
    };
    hipLaunchCooperativeKernel((const void*)lstm_kernel, dim3(NBLOCKS), dim3(256),
                               args, 0, stream);

    head_kernel<<<2048, 256, 0, stream>>>(out + 32768 + HSEQ, W1, b1, W2, b2, out);
}

// Round 2
// 18764.008 us; speedup vs baseline: 1.3954x; 1.3954x over previous
//
#include <hip/hip_runtime.h>

#define HSEQ 16777216   // 32*1024*512
#define NPL 32          // blocks per layer
#define NBLK 64

typedef __attribute__((ext_vector_type(8))) __bf16 bf16x8;
typedef __attribute__((ext_vector_type(4))) float f32x4;

// x (B,T,64) f32 -> xbf [t][m][64] bf16
__global__ __launch_bounds__(256) void prep_x(const float* __restrict__ x,
                                              __bf16* __restrict__ xbf) {
    int idx = blockIdx.x * 256 + threadIdx.x;      // float4 units
    int k4 = idx & 15;
    int t  = (idx >> 4) & 1023;
    int m  = idx >> 14;
    float4 v = ((const float4*)x)[idx];
    __bf16* d = xbf + (size_t)t * 2048 + m * 64 + k4 * 4;
    d[0] = (__bf16)v.x; d[1] = (__bf16)v.y; d[2] = (__bf16)v.z; d[3] = (__bf16)v.w;
}

__device__ inline float sigf(float v) { return 1.f / (1.f + expf(-v)); }

// One layer, persistent. 32 blocks/layer, 512 threads. Weights in registers.
// Wave w: mtile = w&1 (batch half), gate ntile = w>>1. One 16x16 output tile, full K.
template<int LAYER>
__device__ __forceinline__ void run_layer(
    int sub, int tid, int blk,
    const __bf16* __restrict__ xbf,
    const float* __restrict__ Wih, const float* __restrict__ Whh,
    const float* __restrict__ bih, const float* __restrict__ bhh,
    const __bf16* __restrict__ hin_buf,   // layer1 only: h0 double-buffer
    __bf16* __restrict__ hself_buf,
    int* flags,
    float* __restrict__ hs_out, float* __restrict__ cs_out,
    float (*gates)[65], float* biasl)
{
    constexpr int KT = LAYER ? 32 : 18;   // k-tiles of 32 (K=1024 / K=576)
    const int hd0  = sub * 16;
    const int lane = tid & 63;
    const int wid  = tid >> 6;
    const int mtile = wid & 1;
    const int ntile = wid >> 1;           // gate 0..3 (i,f,g,o)
    const int m    = mtile * 16 + (lane & 15);
    const int koff = (lane >> 4) << 3;

    // ---- stage weight B-fragments into registers (once) ----
    bf16x8 wfr[KT];
    {
        const int n   = lane & 15;
        const int row = ntile * 512 + hd0 + n;   // PyTorch gate-stacked row
#pragma unroll
        for (int kt = 0; kt < KT; ++kt) {
            int k0 = kt * 32 + koff;
            const float* wp;
            if (LAYER == 0)
                wp = (k0 < 64) ? (Wih + (size_t)row * 64 + k0)
                               : (Whh + (size_t)row * 512 + (k0 - 64));
            else
                wp = (k0 < 512) ? (Wih + (size_t)row * 512 + k0)
                                : (Whh + (size_t)row * 512 + (k0 - 512));
            float4 f0 = ((const float4*)wp)[0];
            float4 f1 = ((const float4*)wp)[1];
            bf16x8 w;
            w[0]=(__bf16)f0.x; w[1]=(__bf16)f0.y; w[2]=(__bf16)f0.z; w[3]=(__bf16)f0.w;
            w[4]=(__bf16)f1.x; w[5]=(__bf16)f1.y; w[6]=(__bf16)f1.z; w[7]=(__bf16)f1.w;
            wfr[kt] = w;
        }
    }
    if (tid < 64) {
        int rowb = (tid >> 4) * 512 + hd0 + (tid & 15);
        biasl[tid] = bih[rowb] + bhh[rowb];
    }
    __syncthreads();

    const int um = tid >> 4, uq = tid & 15;   // update identity: (batch m, hidden q)
    float creg = 0.f;

    for (int s = 0; s < 1025; ++s) {
        const bool active = LAYER ? (s >= 1) : (s < 1024);
        const int t = LAYER ? (s - 1) : s;

        if (active) {
            const __bf16* hself = hself_buf + ((s & 1) ^ 1) * (32 * 512);
            const __bf16* hin   = LAYER ? (hin_buf + ((s & 1) ^ 1) * (32 * 512)) : nullptr;
            f32x4 acc0 = {0.f, 0.f, 0.f, 0.f};
            f32x4 acc1 = {0.f, 0.f, 0.f, 0.f};
#pragma unroll
            for (int kt = 0; kt < KT; ++kt) {
                const __bf16* ap;
                if (LAYER == 0)
                    ap = (kt < 2) ? (xbf + (size_t)t * 2048 + m * 64 + kt * 32 + koff)
                                  : (hself + m * 512 + (kt * 32 + koff - 64));
                else
                    ap = (kt < 16) ? (hin + m * 512 + kt * 32 + koff)
                                   : (hself + m * 512 + (kt - 16) * 32 + koff);
                bf16x8 a = *(const bf16x8*)ap;
                if (kt & 1) acc1 = __builtin_amdgcn_mfma_f32_16x16x32_bf16(a, wfr[kt], acc1, 0, 0, 0);
                else        acc0 = __builtin_amdgcn_mfma_f32_16x16x32_bf16(a, wfr[kt], acc0, 0, 0, 0);
            }
            f32x4 acc = acc0 + acc1;
#pragma unroll
            for (int r = 0; r < 4; ++r)
                gates[mtile * 16 + ((lane >> 4) << 2) + r][ntile * 16 + (lane & 15)] = acc[r];
        }
        __syncthreads();

        float hval = 0.f, cval = 0.f;
        if (active) {
            float gi = gates[um][uq]      + biasl[uq];
            float gf = gates[um][16 + uq] + biasl[16 + uq];
            float gg = gates[um][32 + uq] + biasl[32 + uq];
            float go = gates[um][48 + uq] + biasl[48 + uq];
            float si = sigf(gi), sf = sigf(gf), so = sigf(go);
            creg = sf * creg + si * tanhf(gg);
            hval = so * tanhf(creg);
            cval = creg;
            (hself_buf + (s & 1) * (32 * 512))[um * 512 + hd0 + uq] = (__bf16)hval;
        }
        __syncthreads();   // drain h stores (vmcnt0) before release

        if (s < 1024) {
            if (tid == 0) {
                __threadfence();   // device release: wbl2 so h visible cross-XCD
                __hip_atomic_store(flags + blk * 16, s + 1, __ATOMIC_RELEASE,
                                   __HIP_MEMORY_SCOPE_AGENT);
            }
            // bulk output stores overlap barrier latency; nontemporal keeps L2 clean
            if (active) {
                __builtin_nontemporal_store(hval, &hs_out[((size_t)um * 1024 + t) * 512 + hd0 + uq]);
                __builtin_nontemporal_store(cval, &cs_out[((size_t)um * 1024 + t) * 512 + hd0 + uq]);
            }
            if (tid < 64) {
                int* fp = flags + tid * 16;
                while (__hip_atomic_load(fp, __ATOMIC_RELAXED, __HIP_MEMORY_SCOPE_AGENT) < s + 1)
                    __builtin_amdgcn_s_sleep(1);
            }
            __syncthreads();
            __threadfence();       // device acquire: invalidate stale L1/L2 before h reads
        } else if (active) {
            __builtin_nontemporal_store(hval, &hs_out[((size_t)um * 1024 + t) * 512 + hd0 + uq]);
            __builtin_nontemporal_store(cval, &cs_out[((size_t)um * 1024 + t) * 512 + hd0 + uq]);
        }
    }
}

__global__ __launch_bounds__(512, 2) void lstm2(
    const __bf16* __restrict__ xbf,
    const float* __restrict__ Wih0, const float* __restrict__ Whh0,
    const float* __restrict__ bih0, const float* __restrict__ bhh0,
    const float* __restrict__ Wih1, const float* __restrict__ Whh1,
    const float* __restrict__ bih1, const float* __restrict__ bhh1,
    __bf16* __restrict__ h0buf, __bf16* __restrict__ h1buf,
    int* flags, float* __restrict__ dout)
{
    __shared__ float gates[32][65];
    __shared__ float biasl[64];
    const int tid = threadIdx.x, blk = blockIdx.x;
    float* hsbase = dout + 32768;
    if (blk < NPL)
        run_layer<0>(blk, tid, blk, xbf, Wih0, Whh0, bih0, bhh0, nullptr, h0buf,
                     flags, hsbase, hsbase + 2 * (size_t)HSEQ, gates, biasl);
    else
        run_layer<1>(blk - NPL, tid, blk, xbf, Wih1, Whh1, bih1, bhh1, h0buf, h1buf,
                     flags, hsbase + (size_t)HSEQ, hsbase + 3 * (size_t)HSEQ, gates, biasl);
}

// out[tok] = W2 @ relu(W1 @ h1[tok] + b1) + b2 ; 16 tokens per block
__global__ __launch_bounds__(256) void head_kernel(
    const float* __restrict__ h1s, const float* __restrict__ W1,
    const float* __restrict__ b1,  const float* __restrict__ W2,
    const float* __restrict__ b2,  float* __restrict__ out)
{
    __shared__ alignas(16) float hl[16][512];
    __shared__ float red[16][257];
    const int tid = threadIdx.x;
    const size_t tok0 = (size_t)blockIdx.x * 16;

    const float4* src = (const float4*)(h1s + tok0 * 512);
    float4* dst = (float4*)(&hl[0][0]);
    for (int i = tid; i < 2048; i += 256) dst[i] = src[i];
    __syncthreads();

    float acc[16];
#pragma unroll
    for (int i = 0; i < 16; ++i) acc[i] = 0.f;
    const float4* wrow = (const float4*)(W1 + (size_t)tid * 512);
    for (int k4 = 0; k4 < 128; ++k4) {
        float4 w = wrow[k4];
#pragma unroll
        for (int i = 0; i < 16; ++i) {
            float4 h = ((const float4*)&hl[i][0])[k4];
            acc[i] += w.x * h.x + w.y * h.y + w.z * h.z + w.w * h.w;
        }
    }
    float w2 = W2[tid];
    float bb1 = b1[tid];
#pragma unroll
    for (int i = 0; i < 16; ++i) {
        float hid = acc[i] + bb1;
        red[i][tid] = w2 * (hid > 0.f ? hid : 0.f);
    }
    __syncthreads();
    if (tid < 16) {
        float ssum = b2[0];
        for (int j = 0; j < 256; ++j) ssum += red[tid][j];
        out[tok0 + tid] = ssum;
    }
}

extern "C" void kernel_launch(void* const* d_in, const int* in_sizes, int n_in,
                              void* d_out, int out_size, void* d_ws, size_t ws_size,
                              hipStream_t stream) {
    const float* x    = (const float*)d_in[0];
    const float* Wih0 = (const float*)d_in[1];
    const float* Whh0 = (const float*)d_in[2];
    const float* bih0 = (const float*)d_in[3];
    const float* bhh0 = (const float*)d_in[4];
    const float* Wih1 = (const float*)d_in[5];
    const float* Whh1 = (const float*)d_in[6];
    const float* bih1 = (const float*)d_in[7];
    const float* bhh1 = (const float*)d_in[8];
    const float* W1   = (const float*)d_in[9];
    const float* b1   = (const float*)d_in[10];
    const float* W2   = (const float*)d_in[11];
    const float* b2   = (const float*)d_in[12];
    float* out = (float*)d_out;

    char* ws = (char*)d_ws;
    int*     flags = (int*)ws;                          // 64 flags, 64B stride
    __bf16* h0buf = (__bf16*)(ws + 4096);               // 2 x 32x512 bf16
    __bf16* h1buf = (__bf16*)(ws + 4096 + 65536);
    __bf16* xbf   = (__bf16*)(ws + 4096 + 131072);      // 4 MB

    hipMemsetAsync(ws, 0, 4096 + 131072, stream);       // flags + h double-buffers

    prep_x<<<2048, 256, 0, stream>>>(x, xbf);

    const __bf16* xbf_c = xbf;
    void* args[] = {
        (void*)&xbf_c,
        (void*)&Wih0, (void*)&Whh0, (void*)&bih0, (void*)&bhh0,
        (void*)&Wih1, (void*)&Whh1, (void*)&bih1, (void*)&bhh1,
        (void*)&h0buf, (void*)&h1buf, (void*)&flags, (void*)&out
    };
    hipLaunchCooperativeKernel((const void*)lstm2, dim3(NBLK), dim3(512),
                               args, 0, stream);

    head_kernel<<<2048, 256, 0, stream>>>(out + 32768 + (size_t)HSEQ, W1, b1, W2, b2, out);
}

// Round 3
// 3953.341 us; speedup vs baseline: 6.6232x; 4.7464x over previous
//
#include <hip/hip_runtime.h>

#define HSEQ 16777216   // 32*1024*512
#define NPL 32          // blocks per layer
#define NBLK 64

typedef __attribute__((ext_vector_type(8))) __bf16 bf16x8;
typedef __attribute__((ext_vector_type(4))) float f32x4;
typedef unsigned long long u64;

// x (B,T,64) f32 -> xbf [t][m][64] bf16
__global__ __launch_bounds__(256) void prep_x(const float* __restrict__ x,
                                              __bf16* __restrict__ xbf) {
    int idx = blockIdx.x * 256 + threadIdx.x;      // float4 units
    int k4 = idx & 15;
    int t  = (idx >> 4) & 1023;
    int m  = idx >> 14;
    float4 v = ((const float4*)x)[idx];
    __bf16* d = xbf + (size_t)t * 2048 + m * 64 + k4 * 4;
    d[0] = (__bf16)v.x; d[1] = (__bf16)v.y; d[2] = (__bf16)v.z; d[3] = (__bf16)v.w;
}

__device__ inline float sigf(float v) { return 1.f / (1.f + expf(-v)); }

// LLC-coherent (sc0 sc1) 8B accesses: bypass non-coherent per-XCD L2, no fences needed.
__device__ __forceinline__ u64 llc_load(const u64* p) {
    return __hip_atomic_load(p, __ATOMIC_RELAXED, __HIP_MEMORY_SCOPE_AGENT);
}
__device__ __forceinline__ void llc_store(u64* p, u64 v) {
    __hip_atomic_store(p, v, __ATOMIC_RELAXED, __HIP_MEMORY_SCOPE_AGENT);
}

// Store one 8B chunk (4 bf16) of A[m][k0..k0+4) into packed MFMA fragment layout in LDS.
// Fragment slot (kt, mtile, lane) holds A[mtile*16+(lane&15)][kt*32+(lane>>4)*8 ..+8] (16B).
// XOR-swizzle bits 4-6 of the byte address to balance LDS banks on read and write.
__device__ __forceinline__ void stfrag(char* smem, int kt_base, int m, int kc4, u64 v) {
    int k0   = kc4 << 2;
    int kt   = kt_base + (k0 >> 5);
    int sub  = (k0 >> 3) & 3;
    int half = (k0 >> 2) & 1;
    int slot = ((kt << 1) + (m >> 4)) * 64 + (sub << 4) + (m & 15);
    int byte = ((slot << 4) ^ (((slot >> 7) & 7) << 4)) + (half << 3);
    *(u64*)(smem + byte) = v;
}

// One layer, persistent. 32 blocks/layer, 512 threads. Weights in registers.
// Wave w: mtile = w&1 (batch half), ntile = w>>1 (gate i,f,g,o). 16x16 tile, full K.
template<int LAYER>
__device__ __forceinline__ void run_layer(
    int sub, int tid, int blk,
    const __bf16* __restrict__ xbf,
    const float* __restrict__ Wih, const float* __restrict__ Whh,
    const float* __restrict__ bih, const float* __restrict__ bhh,
    const __bf16* __restrict__ hin_buf,   // layer1 only: h0 double-buffer
    __bf16* __restrict__ hself_buf,
    int* flags,
    float* __restrict__ hs_out, float* __restrict__ cs_out,
    char* smem)
{
    constexpr int KT = LAYER ? 32 : 18;   // k-tiles of 32 (K=1024 / K=576)
    const int hd0   = sub * 16;
    const int lane  = tid & 63;
    const int wid   = tid >> 6;
    const int mtile = wid & 1;
    const int ntile = wid >> 1;
    const int koff  = (lane >> 4) << 3;

    // ---- stage weight B-fragments into registers (once, plain cached loads) ----
    bf16x8 wfr[KT];
    {
        const int n   = lane & 15;
        const int row = ntile * 512 + hd0 + n;   // PyTorch gate-stacked row
#pragma unroll
        for (int kt = 0; kt < KT; ++kt) {
            int k0 = kt * 32 + koff;
            const float* wp;
            if (LAYER == 0)
                wp = (k0 < 64) ? (Wih + (size_t)row * 64 + k0)
                               : (Whh + (size_t)row * 512 + (k0 - 64));
            else
                wp = (k0 < 512) ? (Wih + (size_t)row * 512 + k0)
                                : (Whh + (size_t)row * 512 + (k0 - 512));
            float4 f0 = ((const float4*)wp)[0];
            float4 f1 = ((const float4*)wp)[1];
            bf16x8 w;
            w[0]=(__bf16)f0.x; w[1]=(__bf16)f0.y; w[2]=(__bf16)f0.z; w[3]=(__bf16)f0.w;
            w[4]=(__bf16)f1.x; w[5]=(__bf16)f1.y; w[6]=(__bf16)f1.z; w[7]=(__bf16)f1.w;
            wfr[kt] = w;
        }
    }
    const int um = tid >> 4, uq = tid & 15;   // update identity: (batch m, hidden q)
    const float bi0 = bih[hd0 + uq]        + bhh[hd0 + uq];
    const float bi1 = bih[512 + hd0 + uq]  + bhh[512 + hd0 + uq];
    const float bi2 = bih[1024 + hd0 + uq] + bhh[1024 + hd0 + uq];
    const float bi3 = bih[1536 + hd0 + uq] + bhh[1536 + hd0 + uq];
    float creg = 0.f;

    float*  gates  = (float*)smem;             // [32][65], time-shares frag region
    __bf16* hstage = (__bf16*)(smem + 8448);   // [32][16], time-shares frag region

    for (int s = 0; s < 1025; ++s) {
        const bool active = LAYER ? (s >= 1) : (s < 1024);
        const int t = LAYER ? (s - 1) : s;

        // ---- grid barrier: everyone finished superstep s-1 (flags are LLC-coherent) ----
        if (s > 0 && tid < NBLK) {
            int* fp = flags + tid * 16;
            while (__hip_atomic_load(fp, __ATOMIC_RELAXED, __HIP_MEMORY_SCOPE_AGENT) < s)
                __builtin_amdgcn_s_sleep(1);
        }
        __syncthreads();

        // ---- stage A (x | h) into packed LDS fragments ----
        if (active) {
            if (LAYER == 0) {
                u64 vx = *(const u64*)(xbf + (size_t)t * 2048 + (tid >> 4) * 64 + (tid & 15) * 4);
                const u64* hs = (const u64*)(hself_buf + ((s & 1) ^ 1) * (32 * 512));
                u64 v[8];
#pragma unroll
                for (int i = 0; i < 8; ++i) v[i] = llc_load(hs + tid + i * 512);
                stfrag(smem, 0, tid >> 4, tid & 15, vx);
#pragma unroll
                for (int i = 0; i < 8; ++i) {
                    int c = tid + i * 512;
                    stfrag(smem, 2, c >> 7, c & 127, v[i]);
                }
            } else {
                const u64* h0 = (const u64*)(hin_buf + ((s & 1) ^ 1) * (32 * 512));
                const u64* h1 = (const u64*)(hself_buf + ((s & 1) ^ 1) * (32 * 512));
                u64 v0[8], v1[8];
#pragma unroll
                for (int i = 0; i < 8; ++i) v0[i] = llc_load(h0 + tid + i * 512);
#pragma unroll
                for (int i = 0; i < 8; ++i) v1[i] = llc_load(h1 + tid + i * 512);
#pragma unroll
                for (int i = 0; i < 8; ++i) {
                    int c = tid + i * 512;
                    stfrag(smem, 0, c >> 7, c & 127, v0[i]);
                }
#pragma unroll
                for (int i = 0; i < 8; ++i) {
                    int c = tid + i * 512;
                    stfrag(smem, 16, c >> 7, c & 127, v1[i]);
                }
            }
        }
        __syncthreads();

        // ---- MFMA: gates tile in registers ----
        f32x4 acc0 = {0.f,0.f,0.f,0.f}, acc1 = {0.f,0.f,0.f,0.f};
        if (active) {
            const int sb = (mtile * 64 + lane) << 4;
#pragma unroll
            for (int kt = 0; kt < KT; ++kt) {
                bf16x8 a = *(const bf16x8*)(smem + ((sb ^ ((kt & 7) << 4)) + kt * 2048));
                if (kt & 1) acc1 = __builtin_amdgcn_mfma_f32_16x16x32_bf16(a, wfr[kt], acc1, 0, 0, 0);
                else        acc0 = __builtin_amdgcn_mfma_f32_16x16x32_bf16(a, wfr[kt], acc0, 0, 0, 0);
            }
        }
        __syncthreads();   // all frag reads done before gates region overwrite

        if (active) {
            f32x4 acc = acc0 + acc1;
#pragma unroll
            for (int r = 0; r < 4; ++r)
                gates[(mtile * 16 + ((lane >> 4) << 2) + r) * 65 + ntile * 16 + (lane & 15)] = acc[r];
        }
        __syncthreads();

        // ---- elementwise update ----
        if (active) {
            float gi = gates[um * 65 + uq]      + bi0;
            float gf = gates[um * 65 + 16 + uq] + bi1;
            float gg = gates[um * 65 + 32 + uq] + bi2;
            float go = gates[um * 65 + 48 + uq] + bi3;
            float si = sigf(gi), sf = sigf(gf), so = sigf(go);
            creg = sf * creg + si * tanhf(gg);
            float hval = so * tanhf(creg);
            hstage[um * 16 + uq] = (__bf16)hval;
            __builtin_nontemporal_store(hval, &hs_out[((size_t)um * 1024 + t) * 512 + hd0 + uq]);
            __builtin_nontemporal_store(creg, &cs_out[((size_t)um * 1024 + t) * 512 + hd0 + uq]);
        }
        __syncthreads();

        // ---- publish h slice to LLC (8B packed) ----
        if (active && tid < 128) {
            int m = tid >> 2, q4 = tid & 3;
            u64 v = *(const u64*)(hstage + m * 16 + q4 * 4);
            u64* hout = (u64*)(hself_buf + (s & 1) * (32 * 512));
            llc_store(hout + m * 128 + (hd0 >> 2) + q4, v);
        }
        __syncthreads();   // drains each wave's vmcnt -> h stores acked at LLC

        if (s < 1024 && tid == 0)
            __hip_atomic_store(flags + blk * 16, s + 1, __ATOMIC_RELAXED, __HIP_MEMORY_SCOPE_AGENT);
    }
}

__global__ __launch_bounds__(512, 1) void lstm2(
    const __bf16* __restrict__ xbf,
    const float* __restrict__ Wih0, const float* __restrict__ Whh0,
    const float* __restrict__ bih0, const float* __restrict__ bhh0,
    const float* __restrict__ Wih1, const float* __restrict__ Whh1,
    const float* __restrict__ bih1, const float* __restrict__ bhh1,
    __bf16* __restrict__ h0buf, __bf16* __restrict__ h1buf,
    int* flags, float* __restrict__ dout)
{
    __shared__ alignas(16) char smem[65536];
    const int tid = threadIdx.x, blk = blockIdx.x;
    float* hsbase = dout + 32768;
    if (blk < NPL)
        run_layer<0>(blk, tid, blk, xbf, Wih0, Whh0, bih0, bhh0, nullptr, h0buf,
                     flags, hsbase, hsbase + 2 * (size_t)HSEQ, smem);
    else
        run_layer<1>(blk - NPL, tid, blk, xbf, Wih1, Whh1, bih1, bhh1, h0buf, h1buf,
                     flags, hsbase + (size_t)HSEQ, hsbase + 3 * (size_t)HSEQ, smem);
}

// out[tok] = W2 @ relu(W1 @ h1[tok] + b1) + b2 ; 16 tokens per block
__global__ __launch_bounds__(256) void head_kernel(
    const float* __restrict__ h1s, const float* __restrict__ W1,
    const float* __restrict__ b1,  const float* __restrict__ W2,
    const float* __restrict__ b2,  float* __restrict__ out)
{
    __shared__ alignas(16) float hl[16][512];
    __shared__ float red[16][257];
    const int tid = threadIdx.x;
    const size_t tok0 = (size_t)blockIdx.x * 16;

    const float4* src = (const float4*)(h1s + tok0 * 512);
    float4* dst = (float4*)(&hl[0][0]);
    for (int i = tid; i < 2048; i += 256) dst[i] = src[i];
    __syncthreads();

    float acc[16];
#pragma unroll
    for (int i = 0; i < 16; ++i) acc[i] = 0.f;
    const float4* wrow = (const float4*)(W1 + (size_t)tid * 512);
    for (int k4 = 0; k4 < 128; ++k4) {
        float4 w = wrow[k4];
#pragma unroll
        for (int i = 0; i < 16; ++i) {
            float4 h = ((const float4*)&hl[i][0])[k4];
            acc[i] += w.x * h.x + w.y * h.y + w.z * h.z + w.w * h.w;
        }
    }
    float w2 = W2[tid];
    float bb1 = b1[tid];
#pragma unroll
    for (int i = 0; i < 16; ++i) {
        float hid = acc[i] + bb1;
        red[i][tid] = w2 * (hid > 0.f ? hid : 0.f);
    }
    __syncthreads();
    if (tid < 16) {
        float ssum = b2[0];
        for (int j = 0; j < 256; ++j) ssum += red[tid][j];
        out[tok0 + tid] = ssum;
    }
}

extern "C" void kernel_launch(void* const* d_in, const int* in_sizes, int n_in,
                              void* d_out, int out_size, void* d_ws, size_t ws_size,
                              hipStream_t stream) {
    const float* x    = (const float*)d_in[0];
    const float* Wih0 = (const float*)d_in[1];
    const float* Whh0 = (const float*)d_in[2];
    const float* bih0 = (const float*)d_in[3];
    const float* bhh0 = (const float*)d_in[4];
    const float* Wih1 = (const float*)d_in[5];
    const float* Whh1 = (const float*)d_in[6];
    const float* bih1 = (const float*)d_in[7];
    const float* bhh1 = (const float*)d_in[8];
    const float* W1   = (const float*)d_in[9];
    const float* b1   = (const float*)d_in[10];
    const float* W2   = (const float*)d_in[11];
    const float* b2   = (const float*)d_in[12];
    float* out = (float*)d_out;

    char* ws = (char*)d_ws;
    int*    flags = (int*)ws;                           // 64 flags, 64B stride
    __bf16* h0buf = (__bf16*)(ws + 4096);               // 2 x 32x512 bf16
    __bf16* h1buf = (__bf16*)(ws + 4096 + 65536);
    __bf16* xbf   = (__bf16*)(ws + 4096 + 131072);      // 4 MB

    hipMemsetAsync(ws, 0, 4096 + 131072, stream);       // flags + h double-buffers

    prep_x<<<2048, 256, 0, stream>>>(x, xbf);

    const __bf16* xbf_c = xbf;
    void* args[] = {
        (void*)&xbf_c,
        (void*)&Wih0, (void*)&Whh0, (void*)&bih0, (void*)&bhh0,
        (void*)&Wih1, (void*)&Whh1, (void*)&bih1, (void*)&bhh1,
        (void*)&h0buf, (void*)&h1buf, (void*)&flags, (void*)&out
    };
    hipLaunchCooperativeKernel((const void*)lstm2, dim3(NBLK), dim3(512),
                               args, 0, stream);

    head_kernel<<<2048, 256, 0, stream>>>(out + 32768 + (size_t)HSEQ, W1, b1, W2, b2, out);
}